// Round 10
// baseline (203.450 us; speedup 1.0000x reference)
//
#include <hip/hip_runtime.h>
#include <hip/hip_bf16.h>

#define KK 5
constexpr int N0 = 78400;     // B*28*28
constexpr int E0 = 627200;    // N0*8
constexpr int N1 = 19600;     // B*14*14
constexpr int E1 = 156800;    // N1*8
constexpr int C1 = 32, C2 = 64;
constexpr int BSZ = 100;
constexpr int FC1_IN = 3136, FC1_OUT = 512;
constexpr int NKEYS = 98000;  // N0 + N1 global node keys
constexpr int NCOARSE = 383;  // coarse buckets of 256 keys
constexpr int CAPB = 2400;    // bucket capacity: Poisson(2048) + 7.7 sigma
constexpr int KEXT = 832;     // 800 tap-space + 32 root channels
constexpr int ULS = 836;      // LDS fp32 U row stride
constexpr int UBS = 856;      // LDS bf16 U row stride (ushorts)
constexpr int CH2 = 160;      // conv2 edge staging chunk (LDS: +ev fits 2 blk/CU)
constexpr int CH1 = 640;      // conv1 edge staging chunk
constexpr int KZ = 7;         // fc1 K-splits (448 K each = 2 chunks x 224)

typedef __attribute__((ext_vector_type(8))) short bf16x8;
typedef __attribute__((ext_vector_type(4))) float f32x4;

__device__ __forceinline__ unsigned short f2bf(float f) {
    union { float f; unsigned u; } v; v.f = f;
    unsigned u = v.u;
    unsigned r = (u + 0x7FFF + ((u >> 16) & 1)) >> 16;   // RNE
    return (unsigned short)r;
}

__device__ __forceinline__ void taps4(float px, float py,
                                      int& a00, int& a01, int& a10, int& a11,
                                      float& fx, float& fy) {
    float kfx = floorf(px), kfy = floorf(py);
    fx = px - kfx; fy = py - kfy;
    int k0x = min(max((int)kfx, 0), KK - 1);
    int k0y = min(max((int)kfy, 0), KK - 1);
    int k1x = min(k0x + 1, KK - 1), k1y = min(k0y + 1, KK - 1);
    a00 = k0x * KK + k0y; a01 = k0x * KK + k1y;
    a10 = k1x * KK + k0y; a11 = k1x * KK + k1y;
}

// ---- sort A + weight prep merged. Blocks 0..191: LDS-histogram coarse
//      binning. Edge payload {src|lowkey<<20, px16|py16} read HERE
//      (sequentially) and carried through the sort, so conv kernels never
//      do random ei*/ps* gathers. Blocks 192..583: wt1 transpose. 584..591: w2t.
__global__ void coarse_bin(const int* __restrict__ ei0, const int* __restrict__ ei1,
                           const float* __restrict__ ps0, const float* __restrict__ ps1,
                           int* __restrict__ gcur, int2* __restrict__ pk2,
                           const float* __restrict__ fc1w, const float* __restrict__ W2,
                           const float* __restrict__ root2,
                           unsigned short* __restrict__ wt1,
                           unsigned short* __restrict__ w2t) {
    __shared__ int hist[NCOARSE];
    __shared__ int gbase[NCOARSE];
    __shared__ unsigned short tile[64 * 66];
    int t = threadIdx.x;               // 512 threads
    if (blockIdx.x >= 192) {
        int pb = blockIdx.x - 192;
        if (pb >= 392) {               // w2t: 8 blocks x 6656 elems
            int base = (pb - 392) * 6656;
            for (int i2 = t; i2 < 6656; i2 += 512) {
                int idx = base + i2;
                int o = idx / KEXT, k = idx - o * KEXT;
                float v = (k < 800) ? W2[k * 64 + o] : root2[(k - 800) * 64 + o];
                w2t[idx] = f2bf(v);
            }
            return;
        }
        // wt1 transpose: 392 blocks = 49 k-tiles x 8 j-tiles
        int k0 = (pb >> 3) * 64, j0 = (pb & 7) * 64;
        int jj = t & 63, ks = t >> 6;  // ks 0..7
        for (int kk = ks; kk < 64; kk += 8)
            tile[kk * 66 + jj] = f2bf(fc1w[(k0 + kk) * FC1_OUT + j0 + jj]);
        __syncthreads();
        int kk2 = t & 63, js = t >> 6;
        for (int j2 = js; j2 < 64; j2 += 8)
            wt1[(j0 + j2) * FC1_IN + k0 + kk2] = tile[kk2 * 66 + j2];
        return;
    }
    for (int i = t; i < NCOARSE; i += 512) hist[i] = 0;
    __syncthreads();
    int e0b = blockIdx.x * 4096;
    int keys[8], rnk[8], pay0[8], pay1[8];
#pragma unroll
    for (int j = 0; j < 8; j++) {
        int e = e0b + t + j * 512;
        int gk = -1, p0 = 0, p1v = 0;
        if (e < E0) {
            gk = ei0[E0 + e];
            float px = ps0[2 * e] * 4.f, py = ps0[2 * e + 1] * 4.f;
            unsigned ux = min((unsigned)(px * 16384.f + 0.5f), 65535u);
            unsigned uy = min((unsigned)(py * 16384.f + 0.5f), 65535u);
            p0 = ei0[e]; p1v = (int)(ux | (uy << 16));
        } else if (e < E0 + E1) {
            int el = e - E0;
            gk = N0 + ei1[E1 + el];
            float px = ps1[2 * el] * 4.f, py = ps1[2 * el + 1] * 4.f;
            unsigned ux = min((unsigned)(px * 16384.f + 0.5f), 65535u);
            unsigned uy = min((unsigned)(py * 16384.f + 0.5f), 65535u);
            p0 = ei1[el]; p1v = (int)(ux | (uy << 16));
        }
        keys[j] = gk; pay0[j] = p0; pay1[j] = p1v;
    }
#pragma unroll
    for (int j = 0; j < 8; j++)
        if (keys[j] >= 0) rnk[j] = atomicAdd(&hist[keys[j] >> 8], 1);  // native ds_add
    __syncthreads();
    for (int i = t; i < NCOARSE; i += 512)
        gbase[i] = hist[i] ? atomicAdd(&gcur[i], hist[i]) : 0;
    __syncthreads();
#pragma unroll
    for (int j = 0; j < 8; j++) {
        if (keys[j] >= 0) {
            int b = keys[j] >> 8;
            int p = gbase[b] + rnk[j];
            if (p < CAPB)
                pk2[b * CAPB + p] = make_int2(pay0[j] | ((keys[j] & 255) << 20), pay1[j]);
        }
    }
}

// ---- sort C: per-bucket LDS counting sort -> dense erec + off. ----
__global__ void fine_sort(const int2* __restrict__ pk2, const int* __restrict__ gcur,
                          int2* __restrict__ erec, int* __restrict__ off) {
    __shared__ int cl[NCOARSE];    // 1.5 KB
    __shared__ int2 ent[CAPB];     // 19.2 KB
    __shared__ int rnk[CAPB];      // 9.6 KB
    __shared__ int h2[256];
    __shared__ int sc[256];
    __shared__ int redbuf[4];
    __shared__ int baseS;
    int b = blockIdx.x, t = threadIdx.x;   // 256 threads
    for (int i2 = t; i2 < NCOARSE; i2 += 256) cl[i2] = min(gcur[i2], CAPB);
    __syncthreads();
    {   // base = sum cl[0..b-1], 256-thread reduce
        int s = 0;
        if (t < b) s += cl[t];
        if (t + 256 < b) s += cl[t + 256];
#pragma unroll
        for (int o2 = 32; o2 > 0; o2 >>= 1) s += __shfl_down(s, o2);
        if ((t & 63) == 0) redbuf[t >> 6] = s;
        __syncthreads();
        if (t == 0) baseS = redbuf[0] + redbuf[1] + redbuf[2] + redbuf[3];
        __syncthreads();
    }
    int base = baseS;
    int cb = cl[b];
    h2[t] = 0;
    __syncthreads();
    for (int i = t; i < cb; i += 256) {
        int2 v = pk2[b * CAPB + i];
        ent[i] = v;
        rnk[i] = atomicAdd(&h2[(v.x >> 20) & 255], 1);   // native ds_add
    }
    __syncthreads();
    int v0 = h2[t];
    sc[t] = v0;
    __syncthreads();
    for (int d = 1; d < 256; d <<= 1) {
        int add = (t >= d) ? sc[t - d] : 0;
        __syncthreads();
        sc[t] += add;
        __syncthreads();
    }
    int excl = sc[t] - v0;
    __syncthreads();
    sc[t] = excl;
    __syncthreads();
    int n = (b << 8) + t;
    if (n < NKEYS) off[n] = base + excl;
    if (b == 0 && t == 0) off[NKEYS] = E0 + E1;
    for (int i = t; i < cb; i += 256) {
        int2 v = ent[i];
        erec[base + sc[(v.x >> 20) & 255] + rnk[i]] = v;   // src stays in low 20 bits
    }
}

// ---- conv1 + pool1 fused: block = 2 image rows (56 nodes).
//      Edge metadata is a SEQUENTIAL 8B-record stream (no random ei0/ps0). ----
__global__ __launch_bounds__(256, 4)
void conv1_pool(const int2* __restrict__ erec, const int* __restrict__ off,
                const float* __restrict__ x,
                const float* __restrict__ W1,
                const float* __restrict__ root, const float* __restrict__ bias,
                float* __restrict__ p1) {
    __shared__ float S4[224 * 25];    // 22.4 KB quadrant slices; h1 tile aliases
    __shared__ float Sr[56 * 25];     // 5.6 KB reduced
    __shared__ float exv[CH1], efx[CH1], efy[CH1];
    __shared__ int   emt[CH1];
    float* h1t = S4;
    int t = threadIdx.x;
    int bb = blockIdx.x;              // 1400 blocks; nodes bb*56 .. +55
    int n0 = bb * 56;
    int q = t & 3, nl = t >> 2;
    bool actN = nl < 56;
    int n = n0 + (actN ? nl : 0);
    float* sp = S4 + (actN ? (nl * 4 + q) : 0) * 25;
    for (int i = t; i < 224 * 25; i += 256) S4[i] = 0.f;
    int e0 = off[n0], e1 = off[n0 + 56];
    int my0 = off[n], my1 = off[n + 1];
    for (int base = e0; base < e1; base += CH1) {
        int nE = min(e1 - base, CH1);
        __syncthreads();
        for (int j = t; j < nE; j += 256) {
            int2 r = erec[base + j];                  // sequential, coalesced
            int src = r.x & 0xFFFFF;
            float px = (float)((unsigned)r.y & 0xFFFF) * (1.f / 16384.f);
            float py = (float)((unsigned)r.y >> 16) * (1.f / 16384.f);
            int a00, a01, a10, a11; float fx, fy;
            taps4(px, py, a00, a01, a10, a11, fx, fy);
            emt[j] = a00 | (a01 << 5) | (a10 << 10) | (a11 << 15);
            efx[j] = fx; efy[j] = fy;
            exv[j] = x[src];
        }
        __syncthreads();
        if (actN) {
            int r0 = max(my0 - base, 0), r1 = min(my1 - base, nE);
            for (int p = r0 + q; p < r1; p += 4) {
                float xv = exv[p]; int m = emt[p];
                float fx = efx[p], fy = efy[p];
                float gx = 1.f - fx, gy = 1.f - fy;
                sp[m & 31]         += gx * gy * xv;
                sp[(m >> 5) & 31]  += gx * fy * xv;
                sp[(m >> 10) & 31] += fx * gy * xv;
                sp[(m >> 15) & 31] += fx * fy * xv;
            }
        }
    }
    __syncthreads();
    for (int i2 = t; i2 < 56 * 25; i2 += 256) {
        int n2 = i2 / 25, a = i2 - n2 * 25;
        Sr[i2] = S4[(n2 * 4 + 0) * 25 + a] + S4[(n2 * 4 + 1) * 25 + a] +
                 S4[(n2 * 4 + 2) * 25 + a] + S4[(n2 * 4 + 3) * 25 + a];
    }
    __syncthreads();
    {
        int o = t & 31, ng = t >> 5;
        float w1c[25];
#pragma unroll
        for (int a = 0; a < 25; a++) w1c[a] = W1[a * C1 + o];
        float ro = root[o], bo = bias[o];
        for (int j2 = 0; j2 < 7; j2++) {
            int nl2 = ng * 7 + j2;
            int n2 = n0 + nl2;
            float acc = 0.f;
#pragma unroll
            for (int a = 0; a < 25; a++) acc += Sr[nl2 * 25 + a] * w1c[a];
            float invd = 1.f / fmaxf((float)(off[n2 + 1] - off[n2]), 1.f);
            float v = acc * invd + x[n2] * ro + bo;
            h1t[nl2 * 32 + o] = v > 0.f ? v : expm1f(v);
        }
    }
    __syncthreads();
    for (int i2 = t; i2 < 448; i2 += 256) {
        int o2 = i2 & 31, pc = i2 >> 5;
        float m0 = h1t[(2 * pc) * 32 + o2],      m1 = h1t[(2 * pc + 1) * 32 + o2];
        float m2 = h1t[(28 + 2 * pc) * 32 + o2], m3 = h1t[(28 + 2 * pc + 1) * 32 + o2];
        p1[(bb * 14 + pc) * C1 + o2] = fmaxf(fmaxf(m0, m1), fmaxf(m2, m3));
    }
}

// ---- conv2 fused (MFMA): 16 nodes/block, 512 threads, 2 blocks/CU.
//  Phase 1 restructured: stage -> COOPERATIVE gather (all 512 threads pull
//  edge rows p1[src] into LDS ev[], 4 loads in flight per thread = 2048 per
//  block, latency pipelined) -> per-node accumulate from LDS (~40cy chain
//  steps instead of ~600-900cy remote-L2 round-trips). ----
__global__ __launch_bounds__(512, 4)
void conv2_fused(const float* __restrict__ p1, const int2* __restrict__ erec,
                 const int* __restrict__ off,
                 const unsigned short* __restrict__ w2t,
                 const float* __restrict__ b2, float* __restrict__ h2) {
    __shared__ float Ul[16 * ULS];          // 53.5 KB (bf16 view aliases this)
    __shared__ float ev[CH2 * 32];          // 20.0 KB gathered edge rows
    __shared__ int   es[CH2];
    __shared__ int   et[CH2];
    __shared__ float efx[CH2], efy[CH2];
    unsigned short* Ub = (unsigned short*)Ul;
    int t = threadIdx.x;
    int nb = blockIdx.x * 16;               // 1225 blocks; nodes nb..nb+15
    int i = t & 31;                         // channel
    int g = t >> 5;                         // node 0..15 (also gather edge-slot)
    float* up = Ul + g * ULS;
#pragma unroll
    for (int a = 0; a < 25; a++) up[a * 32 + i] = 0.f;
    up[800 + i] = p1[(nb + g) * C1 + i];    // root channels
    int e0 = off[N0 + nb], e1 = off[N0 + nb + 16];
    int my0 = off[N0 + nb + g], my1 = off[N0 + nb + g + 1];
    for (int base = e0; base < e1; base += CH2) {
        int nE = min(e1 - base, CH2);
        __syncthreads();
        for (int j = t; j < nE; j += 512) {
            int2 r = erec[base + j];                  // sequential, coalesced
            es[j] = r.x & 0xFFFFF;
            float px = (float)((unsigned)r.y & 0xFFFF) * (1.f / 16384.f);
            float py = (float)((unsigned)r.y >> 16) * (1.f / 16384.f);
            int a00, a01, a10, a11; float fx, fy;
            taps4(px, py, a00, a01, a10, a11, fx, fy);
            et[j] = a00 | (a01 << 5) | (a10 << 10) | (a11 << 15);
            efx[j] = fx; efy[j] = fy;
        }
        __syncthreads();
        // cooperative gather: 16 edge-slots x 32 ch, x4 unrolled (4 in flight)
        for (int j0 = g; j0 < nE; j0 += 64) {
            int ja = j0, jb = j0 + 16, jc = j0 + 32, jd = j0 + 48;
            bool vb = jb < nE, vc = jc < nE, vd = jd < nE;
            int sa = es[ja];
            int sb = vb ? es[jb] : sa;
            int sc2 = vc ? es[jc] : sa;
            int sd = vd ? es[jd] : sa;
            float xa = p1[sa * C1 + i];     // all 4 issued before any use
            float xb = p1[sb * C1 + i];
            float xc = p1[sc2 * C1 + i];
            float xd = p1[sd * C1 + i];
            ev[ja * 32 + i] = xa;
            if (vb) ev[jb * 32 + i] = xb;
            if (vc) ev[jc * 32 + i] = xc;
            if (vd) ev[jd * 32 + i] = xd;
        }
        __syncthreads();
        // per-node accumulate from LDS (short, fast chain)
        int r0 = max(my0 - base, 0);
        int r1 = min(my1 - base, nE);
        for (int p = r0; p < r1; p++) {
            float xv = ev[p * 32 + i];
            int m = et[p];
            float fx = efx[p], fy = efy[p];
            float gx = 1.f - fx, gy = 1.f - fy;
            up[(m & 31) * 32 + i]         += gx * gy * xv;
            up[((m >> 5) & 31) * 32 + i]  += gx * fy * xv;
            up[((m >> 10) & 31) * 32 + i] += fx * gy * xv;
            up[((m >> 15) & 31) * 32 + i] += fx * fy * xv;
        }
    }
    __syncthreads();
    // phase 1.5: fp32 -> bf16 once (invd folded into tap part)
    {
        int g2 = t >> 5, i2c = t & 31;
        int dgc = off[N0 + nb + g2 + 1] - off[N0 + nb + g2];
        float invd = 1.f / fmaxf((float)dgc, 1.f);
        const float* srcp = Ul + g2 * ULS + i2c * 26;
        float rv[26];
#pragma unroll
        for (int j = 0; j < 26; j++) {
            float v = srcp[j];
            rv[j] = (i2c * 26 + j < 800) ? v * invd : v;
        }
        __syncthreads();
        unsigned* dstp = (unsigned*)(Ub + g2 * UBS + i2c * 26);
#pragma unroll
        for (int j = 0; j < 13; j++) {
            unsigned lo = f2bf(rv[2 * j]), hi = f2bf(rv[2 * j + 1]);
            dstp[j] = lo | (hi << 16);
        }
    }
    __syncthreads();
    // phase 2: MFMA, waves 0-3. D[node=quad*4+r][o=wv*16+(lane&15)]
    int wv = t >> 6, lane = t & 63, quad = lane >> 4, lrow = lane & 15;
    if (wv < 4) {
        f32x4 acc = {0.f, 0.f, 0.f, 0.f};
        const unsigned short* bbase = w2t + (wv * 16 + lrow) * KEXT;
        const unsigned short* abase = Ub + lrow * UBS;   // A row = node lrow
#pragma unroll
        for (int kc = 0; kc < 26; kc++) {
            bf16x8 a = *(const bf16x8*)(abase + kc * 32 + quad * 8);
            bf16x8 b = *(const bf16x8*)(bbase + kc * 32 + quad * 8);
            acc = __builtin_amdgcn_mfma_f32_16x16x32_bf16(a, b, acc, 0, 0, 0);
        }
        int o = wv * 16 + lrow;
        float bo = b2[o];
#pragma unroll
        for (int r = 0; r < 4; r++) {
            int node = quad * 4 + r;
            float v = acc[r] + bo;
            v = v > 0.f ? v : expm1f(v);
            h2[(nb + node) * C2 + o] = v;
        }
    }
}

// ---- pool2 -> bf16 [112 x 3136], rows 100..111 zeroed (M-pad for MFMA) ----
__global__ void pool2b(const float* __restrict__ h2, unsigned short* __restrict__ p2b) {
    int idx = blockIdx.x * blockDim.x + threadIdx.x;
    if (idx >= 112 * FC1_IN) return;
    if (idx >= 100 * FC1_IN) { p2b[idx] = 0; return; }
    int o = idx & 63; int t2 = idx >> 6;
    int c = t2 % 14; int r = (t2 / 14) % 14; int b = t2 / 196;
    const float* base = h2 + (((b * 28 + 2 * r) * 28 + 2 * c) * C2 + o);
    float m = fmaxf(fmaxf(base[0], base[C2]),
                    fmaxf(base[28 * C2], base[28 * C2 + C2]));
    p2b[idx] = f2bf(m);
}

// ---- fc1 MFMA: [112,3136]bf16 @ wt1^T -> z1p fp32 partials (7 kz splits). ----
__global__ void gemm_fc1(const unsigned short* __restrict__ p2b,
                         const unsigned short* __restrict__ wt1,
                         float* __restrict__ z1p) {
    constexpr int AS = 232;
    __shared__ unsigned short as_[16 * AS];
    int t = threadIdx.x;
    int jt = blockIdx.x, mt = blockIdx.y, kz = blockIdx.z;
    int wv = t >> 6, lane = t & 63, quad = lane >> 4, lrow = lane & 15;
    int m0 = mt * 16;
    int kbase = kz * 448;
    const unsigned short* bbase = wt1 + (jt * 64 + wv * 16 + lrow) * FC1_IN + kbase;
    f32x4 acc = {0.f, 0.f, 0.f, 0.f};
    for (int ch = 0; ch < 2; ch++) {
        __syncthreads();
        for (int slot = t; slot < 448; slot += 256) {
            int r = slot / 28, c = slot - (slot / 28) * 28;
            *(uint4*)(as_ + r * AS + c * 8) =
                *(const uint4*)(p2b + (m0 + r) * FC1_IN + kbase + ch * 224 + c * 8);
        }
        __syncthreads();
        const unsigned short* ab = as_ + lrow * AS;
        const unsigned short* bb = bbase + ch * 224;
#pragma unroll
        for (int kk = 0; kk < 7; kk++) {
            bf16x8 a = *(const bf16x8*)(ab + kk * 32 + quad * 8);
            bf16x8 b = *(const bf16x8*)(bb + kk * 32 + quad * 8);
            acc = __builtin_amdgcn_mfma_f32_16x16x32_bf16(a, b, acc, 0, 0, 0);
        }
    }
    int n = jt * 64 + wv * 16 + lrow;
#pragma unroll
    for (int r = 0; r < 4; r++) {
        int m = m0 + quad * 4 + r;
        z1p[kz * (112 * FC1_OUT) + m * FC1_OUT + n] = acc[r];
    }
}

// ---- fc2 + log_softmax fused; sums 7 fc1 partials, applies fc1 bias+ELU ----
__global__ void fc2_lsm(const float* __restrict__ z1p, const float* __restrict__ fc1b,
                        const float* __restrict__ w, const float* __restrict__ fc2b,
                        float* __restrict__ out) {
    int b = blockIdx.x;
    int t = threadIdx.x;
    int wv = t >> 6;
    int lane = t & 63;
    float acc = 0.f;
#pragma unroll
    for (int m = 0; m < 8; m++) {
        int k = lane * 8 + m;
        float xv = fc1b[k];
#pragma unroll
        for (int p = 0; p < KZ; p++)
            xv += z1p[p * (112 * FC1_OUT) + b * FC1_OUT + k];
        xv = xv > 0.f ? xv : expm1f(xv);
        acc += xv * w[k * 10 + wv];
    }
#pragma unroll
    for (int off = 32; off > 0; off >>= 1) acc += __shfl_down(acc, off);
    __shared__ float zs[10];
    if (lane == 0) {
        float z = acc + fc2b[wv];
        zs[wv] = z > 0.f ? z : expm1f(z);
    }
    __syncthreads();
    if (t < 10) {
        float m = -1e30f;
        for (int jj = 0; jj < 10; jj++) m = fmaxf(m, zs[jj]);
        float s = 0.f;
        for (int jj = 0; jj < 10; jj++) s += expf(zs[jj] - m);
        out[b * 10 + t] = zs[t] - m - logf(s);
    }
}

extern "C" void kernel_launch(void* const* d_in, const int* in_sizes, int n_in,
                              void* d_out, int out_size, void* d_ws, size_t ws_size,
                              hipStream_t stream) {
    const float* x     = (const float*)d_in[0];
    const float* ps0   = (const float*)d_in[1];
    const float* ps1   = (const float*)d_in[2];
    const float* W1    = (const float*)d_in[3];
    const float* root1 = (const float*)d_in[4];
    const float* b1    = (const float*)d_in[5];
    const float* W2    = (const float*)d_in[6];
    const float* root2 = (const float*)d_in[7];
    const float* b2v   = (const float*)d_in[8];
    const float* fc1w  = (const float*)d_in[9];
    const float* fc1b  = (const float*)d_in[10];
    const float* fc2w  = (const float*)d_in[11];
    const float* fc2b  = (const float*)d_in[12];
    const int*   ei0   = (const int*)d_in[13];
    const int*   ei1   = (const int*)d_in[14];

    // Workspace layout — ALL extents in 4-byte WORDS (ushort arrays: count/2).
    // w2t = 64*832 ushorts  = 53,248 us = 26,624 words
    // wt1 = 512*3136 ushorts = 1,605,632 us = 802,816 words
    // p2b = 112*3136 ushorts = 351,232 us = 175,616 words
    float* ws = (float*)d_ws;
    int*  gcur = (int*)ws;                          //        384  (memset region)
    int*  off  = (int*)(ws + 384);                  //     98,001 (pad -> 98,388)
    int2* pk2  = (int2*)(ws + 98388);               //  1,838,400 w (383 x 2400 x 2)
    int2* erec = (int2*)(ws + 1936788);             //  1,568,000 w (784,000 x 2)
    float* p1  = ws + 3504788;                      //    627,200
    float* h2  = ws + 4131988;                      //  1,254,400
    unsigned short* p2b = (unsigned short*)(ws + 5386388);  // 175,616 words
    float* z1p = ws + 5562004;                      //    401,408 (7 partials)
    unsigned short* w2t = (unsigned short*)(ws + 5963412);  //  26,624 words
    unsigned short* wt1 = (unsigned short*)(ws + 5990036);  // 802,816 words
    // high water: 6,792,852 words = 27.2 MB

    hipMemsetAsync(gcur, 0, (size_t)NCOARSE * sizeof(int), stream);

    coarse_bin<<<592, 512, 0, stream>>>(ei0, ei1, ps0, ps1, gcur, pk2,
                                        fc1w, W2, root2, wt1, w2t);
    fine_sort<<<NCOARSE, 256, 0, stream>>>(pk2, gcur, erec, off);
    conv1_pool<<<1400, 256, 0, stream>>>(erec, off, x, W1, root1, b1, p1);
    conv2_fused<<<N1 / 16, 512, 0, stream>>>(p1, erec, off, w2t, b2v, h2);
    pool2b<<<(112 * FC1_IN + 255) / 256, 256, 0, stream>>>(h2, p2b);
    gemm_fc1<<<dim3(8, 7, KZ), 256, 0, stream>>>(p2b, wt1, z1p);
    fc2_lsm<<<BSZ, 640, 0, stream>>>(z1p, fc1b, fc2w, fc2b, (float*)d_out);
}

// Round 11
// 186.427 us; speedup vs baseline: 1.0913x; 1.0913x over previous
//
#include <hip/hip_runtime.h>
#include <hip/hip_bf16.h>

#define KK 5
constexpr int N0 = 78400;     // B*28*28
constexpr int E0 = 627200;    // N0*8
constexpr int N1 = 19600;     // B*14*14
constexpr int E1 = 156800;    // N1*8
constexpr int C1 = 32, C2 = 64;
constexpr int BSZ = 100;
constexpr int FC1_IN = 3136, FC1_OUT = 512;
constexpr int KEXT = 832;     // 800 tap-space + 32 root channels
constexpr int ULS = 836;      // LDS int/fp32 U row stride
constexpr int UBS = 856;      // LDS bf16 U row stride (ushorts)
constexpr int KZ = 7;         // fc1 K-splits

// block-granularity buckets (no fine sort; conv blocks consume unordered)
constexpr int NB0 = 1400;     // E0: 56-node buckets (conv1 block = bucket)
constexpr int CAP0 = 576;     // mean 448 + 6 sigma
constexpr int NB1 = 1225;     // E1: 16-node buckets (conv2 block = bucket)
constexpr int CAP1 = 224;     // mean 128 + 8.5 sigma
constexpr int NBT = NB0 + NB1;  // 2625 counters

constexpr float SC1  = 4194304.f;  // 2^22 conv1 fixed-point scale (r8-proven)
constexpr float ISC1 = 1.f / 4194304.f;
constexpr float SC2  = 1048576.f;  // 2^20 conv2 scale (range headroom)
constexpr float ISC2 = 1.f / 1048576.f;

typedef __attribute__((ext_vector_type(8))) short bf16x8;
typedef __attribute__((ext_vector_type(4))) float f32x4;

__device__ __forceinline__ unsigned short f2bf(float f) {
    union { float f; unsigned u; } v; v.f = f;
    unsigned u = v.u;
    unsigned r = (u + 0x7FFF + ((u >> 16) & 1)) >> 16;   // RNE
    return (unsigned short)r;
}

__device__ __forceinline__ void taps4(float px, float py,
                                      int& a00, int& a01, int& a10, int& a11,
                                      float& fx, float& fy) {
    float kfx = floorf(px), kfy = floorf(py);
    fx = px - kfx; fy = py - kfy;
    int k0x = min(max((int)kfx, 0), KK - 1);
    int k0y = min(max((int)kfy, 0), KK - 1);
    int k1x = min(k0x + 1, KK - 1), k1y = min(k0y + 1, KK - 1);
    a00 = k0x * KK + k0y; a01 = k0x * KK + k1y;
    a10 = k1x * KK + k0y; a11 = k1x * KK + k1y;
}

// ---- single-pass binning + weight prep. Blocks 0..191: scatter edges into
//      per-conv-block buckets (LDS histogram -> one global atomicAdd per
//      nonzero bucket -> contiguous runs). Payload {src|low<<20, px16|py16}.
//      Blocks 192..583: wt1 transpose. 584..591: w2t. NO fine sort needed:
//      conv kernels accumulate with associative int atomics (order-free).
__global__ void coarse_bin(const int* __restrict__ ei0, const int* __restrict__ ei1,
                           const float* __restrict__ ps0, const float* __restrict__ ps1,
                           int* __restrict__ gcur,
                           int2* __restrict__ pk0, int2* __restrict__ pk1,
                           const float* __restrict__ fc1w, const float* __restrict__ W2,
                           const float* __restrict__ root2,
                           unsigned short* __restrict__ wt1,
                           unsigned short* __restrict__ w2t) {
    __shared__ int hist[NBT];          // 10.5 KB
    __shared__ int gbase[NBT];         // 10.5 KB
    __shared__ unsigned short tile[64 * 66];
    int t = threadIdx.x;               // 512 threads
    if (blockIdx.x >= 192) {
        int pb = blockIdx.x - 192;
        if (pb >= 392) {               // w2t: 8 blocks x 6656 elems
            int base = (pb - 392) * 6656;
            for (int i2 = t; i2 < 6656; i2 += 512) {
                int idx = base + i2;
                int o = idx / KEXT, k = idx - o * KEXT;
                float v = (k < 800) ? W2[k * 64 + o] : root2[(k - 800) * 64 + o];
                w2t[idx] = f2bf(v);
            }
            return;
        }
        // wt1 transpose: 392 blocks = 49 k-tiles x 8 j-tiles
        int k0 = (pb >> 3) * 64, j0 = (pb & 7) * 64;
        int jj = t & 63, ks = t >> 6;  // ks 0..7
        for (int kk = ks; kk < 64; kk += 8)
            tile[kk * 66 + jj] = f2bf(fc1w[(k0 + kk) * FC1_OUT + j0 + jj]);
        __syncthreads();
        int kk2 = t & 63, js = t >> 6;
        for (int j2 = js; j2 < 64; j2 += 8)
            wt1[(j0 + j2) * FC1_IN + k0 + kk2] = tile[kk2 * 66 + j2];
        return;
    }
    for (int i = t; i < NBT; i += 512) hist[i] = 0;
    __syncthreads();
    int e0b = blockIdx.x * 4096;
    int keys[8], rnk[8], pay0[8], pay1[8];
#pragma unroll
    for (int j = 0; j < 8; j++) {
        int e = e0b + t + j * 512;
        int k = -1, p0 = 0, p1v = 0;
        if (e < E0) {
            int dst = ei0[E0 + e];
            int b = dst / 56, low = dst - b * 56;       // low: 6 bits
            k = b;
            float px = ps0[2 * e] * 4.f, py = ps0[2 * e + 1] * 4.f;
            unsigned ux = min((unsigned)(px * 16384.f + 0.5f), 65535u);
            unsigned uy = min((unsigned)(py * 16384.f + 0.5f), 65535u);
            p0 = ei0[e] | (low << 20); p1v = (int)(ux | (uy << 16));
        } else if (e < E0 + E1) {
            int el = e - E0;
            int dst = ei1[E1 + el];
            k = NB0 + (dst >> 4);                       // 16-node bucket
            float px = ps1[2 * el] * 4.f, py = ps1[2 * el + 1] * 4.f;
            unsigned ux = min((unsigned)(px * 16384.f + 0.5f), 65535u);
            unsigned uy = min((unsigned)(py * 16384.f + 0.5f), 65535u);
            p0 = ei1[el] | ((dst & 15) << 20); p1v = (int)(ux | (uy << 16));
        }
        keys[j] = k; pay0[j] = p0; pay1[j] = p1v;
    }
#pragma unroll
    for (int j = 0; j < 8; j++)
        if (keys[j] >= 0) rnk[j] = atomicAdd(&hist[keys[j]], 1);   // native ds_add
    __syncthreads();
    for (int i = t; i < NBT; i += 512)
        gbase[i] = hist[i] ? atomicAdd(&gcur[i], hist[i]) : 0;
    __syncthreads();
#pragma unroll
    for (int j = 0; j < 8; j++) {
        if (keys[j] >= 0) {
            int k = keys[j];
            int p = gbase[k] + rnk[j];
            if (k < NB0) {
                if (p < CAP0) pk0[k * CAP0 + p] = make_int2(pay0[j], pay1[j]);
            } else {
                if (p < CAP1) pk1[(k - NB0) * CAP1 + p] = make_int2(pay0[j], pay1[j]);
            }
        }
    }
}

// ---- conv1 + pool1: block = bucket = 56 nodes. Unordered edge consumption
//      via LDS int32 fixed-point atomics (associative -> deterministic;
//      numerics proven in r8 at absmax 0.0156). Then dense matvec + pool. ----
__global__ __launch_bounds__(256, 4)
void conv1_pool(const int2* __restrict__ pk0, const int* __restrict__ cnt0,
                const float* __restrict__ x,
                const float* __restrict__ W1,
                const float* __restrict__ root, const float* __restrict__ bias,
                float* __restrict__ p1) {
    __shared__ int   Ui[56 * 26];     // 5.8 KB fixed-point taps+deg
    __shared__ float h1t[56 * 32];    // 7.2 KB
    int t = threadIdx.x;
    int bb = blockIdx.x;              // 1400 blocks; nodes bb*56 .. +55
    int n0 = bb * 56;
    for (int i = t; i < 56 * 26; i += 256) Ui[i] = 0;
    __syncthreads();
    int cnt = min(cnt0[bb], CAP0);
    const int2* bkt = pk0 + bb * CAP0;
    for (int j = t; j < cnt; j += 256) {
        int2 r = bkt[j];                              // sequential, coalesced
        int src = r.x & 0xFFFFF, low = (r.x >> 20) & 63;
        float px = (float)((unsigned)r.y & 0xFFFF) * (1.f / 16384.f);
        float py = (float)((unsigned)r.y >> 16) * (1.f / 16384.f);
        int a00, a01, a10, a11; float fx, fy;
        taps4(px, py, a00, a01, a10, a11, fx, fy);
        float xv = x[src];                            // 313KB array: L2-resident
        float gx = 1.f - fx, gy = 1.f - fy;
        int* row = Ui + low * 26;
        atomicAdd(row + a00, __float2int_rn(gx * gy * xv * SC1));
        atomicAdd(row + a01, __float2int_rn(gx * fy * xv * SC1));
        atomicAdd(row + a10, __float2int_rn(fx * gy * xv * SC1));
        atomicAdd(row + a11, __float2int_rn(fx * fy * xv * SC1));
        atomicAdd(row + 25, 1);
    }
    __syncthreads();
    {
        int o = t & 31, ng = t >> 5;
        float w1c[25];
#pragma unroll
        for (int a = 0; a < 25; a++) w1c[a] = W1[a * C1 + o];
        float ro = root[o], bo = bias[o];
        for (int j2 = 0; j2 < 7; j2++) {
            int nl = ng * 7 + j2;
            int n = n0 + nl;
            float acc = 0.f;
#pragma unroll
            for (int a = 0; a < 25; a++) acc += (float)Ui[nl * 26 + a] * w1c[a];
            float invd = ISC1 / fmaxf((float)Ui[nl * 26 + 25], 1.f);
            float v = acc * invd + x[n] * ro + bo;
            h1t[nl * 32 + o] = v > 0.f ? v : expm1f(v);
        }
    }
    __syncthreads();
    for (int i2 = t; i2 < 448; i2 += 256) {
        int o2 = i2 & 31, pc = i2 >> 5;
        float m0 = h1t[(2 * pc) * 32 + o2],      m1 = h1t[(2 * pc + 1) * 32 + o2];
        float m2 = h1t[(28 + 2 * pc) * 32 + o2], m3 = h1t[(28 + 2 * pc + 1) * 32 + o2];
        p1[(bb * 14 + pc) * C1 + o2] = fmaxf(fmaxf(m0, m1), fmaxf(m2, m3));
    }
}

// ---- conv2 fused (MFMA): block = bucket = 16 nodes, 512 threads.
//      Phase 1: single-chunk stage, then unordered accumulate via LDS int
//      atomics (no per-node serial walk, no ordering requirement). ----
__global__ __launch_bounds__(512, 2)
void conv2_fused(const float* __restrict__ p1, const int2* __restrict__ pk1,
                 const int* __restrict__ cnt1,
                 const unsigned short* __restrict__ w2t,
                 const float* __restrict__ b2, float* __restrict__ h2) {
    __shared__ int   Ui[16 * ULS];          // 53.5 KB fixed-point (bf16 aliases)
    __shared__ int   es[CAP1];
    __shared__ int   et[CAP1];
    __shared__ float efx[CAP1], efy[CAP1];
    __shared__ int   degc[16];
    unsigned short* Ub = (unsigned short*)Ui;
    int t = threadIdx.x;
    int bx = blockIdx.x;                    // 1225 blocks; nodes bx*16..+15
    int nb = bx * 16;
    int i = t & 31;                         // channel
    int g = t >> 5;                         // node slot 0..15
    int* up = Ui + g * ULS;
#pragma unroll
    for (int a = 0; a < 25; a++) up[a * 32 + i] = 0;
    up[800 + i] = __float2int_rn(p1[(nb + g) * C1 + i] * SC2);   // root channels
    if (t < 16) degc[t] = 0;
    __syncthreads();
    int cnt = min(cnt1[bx], CAP1);
    for (int j = t; j < cnt; j += 512) {
        int2 r = pk1[bx * CAP1 + j];                  // sequential, coalesced
        es[j] = r.x;                                  // src | node<<20
        float px = (float)((unsigned)r.y & 0xFFFF) * (1.f / 16384.f);
        float py = (float)((unsigned)r.y >> 16) * (1.f / 16384.f);
        int a00, a01, a10, a11; float fx, fy;
        taps4(px, py, a00, a01, a10, a11, fx, fy);
        et[j] = a00 | (a01 << 5) | (a10 << 10) | (a11 << 15);
        efx[j] = fx; efy[j] = fy;
        atomicAdd(&degc[(r.x >> 20) & 15], 1);
    }
    __syncthreads();
    // accumulate: thread (slot g, ch i) walks edges g, g+16, ... — all p1
    // loads independent (atomics have no read-back), half-wave coalesced rows.
    for (int j = g; j < cnt; j += 16) {
        int rx = es[j];
        float xv = p1[(rx & 0xFFFFF) * C1 + i];
        int* row = Ui + ((rx >> 20) & 15) * ULS;
        int m = et[j];
        float fx = efx[j], fy = efy[j];
        float gx = 1.f - fx, gy = 1.f - fy;
        atomicAdd(row + (m & 31) * 32 + i,         __float2int_rn(gx * gy * xv * SC2));
        atomicAdd(row + ((m >> 5) & 31) * 32 + i,  __float2int_rn(gx * fy * xv * SC2));
        atomicAdd(row + ((m >> 10) & 31) * 32 + i, __float2int_rn(fx * gy * xv * SC2));
        atomicAdd(row + ((m >> 15) & 31) * 32 + i, __float2int_rn(fx * fy * xv * SC2));
    }
    __syncthreads();
    // phase 1.5: int fixed-point -> bf16 (invd folded into tap part)
    {
        int g2 = t >> 5, i2c = t & 31;
        float invd = 1.f / fmaxf((float)degc[g2], 1.f);
        float stap = ISC2 * invd;
        const int* srcp = Ui + g2 * ULS + i2c * 26;
        float rv[26];
#pragma unroll
        for (int j = 0; j < 26; j++) {
            float v = (float)srcp[j];
            rv[j] = (i2c * 26 + j < 800) ? v * stap : v * ISC2;
        }
        __syncthreads();
        unsigned* dstp = (unsigned*)(Ub + g2 * UBS + i2c * 26);
#pragma unroll
        for (int j = 0; j < 13; j++) {
            unsigned lo = f2bf(rv[2 * j]), hi = f2bf(rv[2 * j + 1]);
            dstp[j] = lo | (hi << 16);
        }
    }
    __syncthreads();
    // phase 2: MFMA, waves 0-3. D[node=quad*4+r][o=wv*16+(lane&15)]
    int wv = t >> 6, lane = t & 63, quad = lane >> 4, lrow = lane & 15;
    if (wv < 4) {
        f32x4 acc = {0.f, 0.f, 0.f, 0.f};
        const unsigned short* bbase = w2t + (wv * 16 + lrow) * KEXT;
        const unsigned short* abase = Ub + lrow * UBS;   // A row = node lrow
#pragma unroll
        for (int kc = 0; kc < 26; kc++) {
            bf16x8 a = *(const bf16x8*)(abase + kc * 32 + quad * 8);
            bf16x8 b = *(const bf16x8*)(bbase + kc * 32 + quad * 8);
            acc = __builtin_amdgcn_mfma_f32_16x16x32_bf16(a, b, acc, 0, 0, 0);
        }
        int o = wv * 16 + lrow;
        float bo = b2[o];
#pragma unroll
        for (int r = 0; r < 4; r++) {
            int node = quad * 4 + r;
            float v = acc[r] + bo;
            v = v > 0.f ? v : expm1f(v);
            h2[(nb + node) * C2 + o] = v;
        }
    }
}

// ---- pool2 -> bf16 [112 x 3136], rows 100..111 zeroed (M-pad for MFMA) ----
__global__ void pool2b(const float* __restrict__ h2, unsigned short* __restrict__ p2b) {
    int idx = blockIdx.x * blockDim.x + threadIdx.x;
    if (idx >= 112 * FC1_IN) return;
    if (idx >= 100 * FC1_IN) { p2b[idx] = 0; return; }
    int o = idx & 63; int t2 = idx >> 6;
    int c = t2 % 14; int r = (t2 / 14) % 14; int b = t2 / 196;
    const float* base = h2 + (((b * 28 + 2 * r) * 28 + 2 * c) * C2 + o);
    float m = fmaxf(fmaxf(base[0], base[C2]),
                    fmaxf(base[28 * C2], base[28 * C2 + C2]));
    p2b[idx] = f2bf(m);
}

// ---- fc1 MFMA: [112,3136]bf16 @ wt1^T -> z1p fp32 partials (7 kz splits). ----
__global__ void gemm_fc1(const unsigned short* __restrict__ p2b,
                         const unsigned short* __restrict__ wt1,
                         float* __restrict__ z1p) {
    constexpr int AS = 232;
    __shared__ unsigned short as_[16 * AS];
    int t = threadIdx.x;
    int jt = blockIdx.x, mt = blockIdx.y, kz = blockIdx.z;
    int wv = t >> 6, lane = t & 63, quad = lane >> 4, lrow = lane & 15;
    int m0 = mt * 16;
    int kbase = kz * 448;
    const unsigned short* bbase = wt1 + (jt * 64 + wv * 16 + lrow) * FC1_IN + kbase;
    f32x4 acc = {0.f, 0.f, 0.f, 0.f};
    for (int ch = 0; ch < 2; ch++) {
        __syncthreads();
        for (int slot = t; slot < 448; slot += 256) {
            int r = slot / 28, c = slot - (slot / 28) * 28;
            *(uint4*)(as_ + r * AS + c * 8) =
                *(const uint4*)(p2b + (m0 + r) * FC1_IN + kbase + ch * 224 + c * 8);
        }
        __syncthreads();
        const unsigned short* ab = as_ + lrow * AS;
        const unsigned short* bb = bbase + ch * 224;
#pragma unroll
        for (int kk = 0; kk < 7; kk++) {
            bf16x8 a = *(const bf16x8*)(ab + kk * 32 + quad * 8);
            bf16x8 b = *(const bf16x8*)(bb + kk * 32 + quad * 8);
            acc = __builtin_amdgcn_mfma_f32_16x16x32_bf16(a, b, acc, 0, 0, 0);
        }
    }
    int n = jt * 64 + wv * 16 + lrow;
#pragma unroll
    for (int r = 0; r < 4; r++) {
        int m = m0 + quad * 4 + r;
        z1p[kz * (112 * FC1_OUT) + m * FC1_OUT + n] = acc[r];
    }
}

// ---- fc2 + log_softmax fused; sums 7 fc1 partials, applies fc1 bias+ELU ----
__global__ void fc2_lsm(const float* __restrict__ z1p, const float* __restrict__ fc1b,
                        const float* __restrict__ w, const float* __restrict__ fc2b,
                        float* __restrict__ out) {
    int b = blockIdx.x;
    int t = threadIdx.x;
    int wv = t >> 6;
    int lane = t & 63;
    float acc = 0.f;
#pragma unroll
    for (int m = 0; m < 8; m++) {
        int k = lane * 8 + m;
        float xv = fc1b[k];
#pragma unroll
        for (int p = 0; p < KZ; p++)
            xv += z1p[p * (112 * FC1_OUT) + b * FC1_OUT + k];
        xv = xv > 0.f ? xv : expm1f(xv);
        acc += xv * w[k * 10 + wv];
    }
#pragma unroll
    for (int off = 32; off > 0; off >>= 1) acc += __shfl_down(acc, off);
    __shared__ float zs[10];
    if (lane == 0) {
        float z = acc + fc2b[wv];
        zs[wv] = z > 0.f ? z : expm1f(z);
    }
    __syncthreads();
    if (t < 10) {
        float m = -1e30f;
        for (int jj = 0; jj < 10; jj++) m = fmaxf(m, zs[jj]);
        float s = 0.f;
        for (int jj = 0; jj < 10; jj++) s += expf(zs[jj] - m);
        out[b * 10 + t] = zs[t] - m - logf(s);
    }
}

extern "C" void kernel_launch(void* const* d_in, const int* in_sizes, int n_in,
                              void* d_out, int out_size, void* d_ws, size_t ws_size,
                              hipStream_t stream) {
    const float* x     = (const float*)d_in[0];
    const float* ps0   = (const float*)d_in[1];
    const float* ps1   = (const float*)d_in[2];
    const float* W1    = (const float*)d_in[3];
    const float* root1 = (const float*)d_in[4];
    const float* b1    = (const float*)d_in[5];
    const float* W2    = (const float*)d_in[6];
    const float* root2 = (const float*)d_in[7];
    const float* b2v   = (const float*)d_in[8];
    const float* fc1w  = (const float*)d_in[9];
    const float* fc1b  = (const float*)d_in[10];
    const float* fc2w  = (const float*)d_in[11];
    const float* fc2b  = (const float*)d_in[12];
    const int*   ei0   = (const int*)d_in[13];
    const int*   ei1   = (const int*)d_in[14];

    // Workspace layout — ALL extents in 4-byte WORDS (ushort arrays: count/2).
    // pk0 = 1400*576 int2 = 1,612,800 w ; pk1 = 1225*224 int2 = 548,800 w
    // p2b = 112*3136 us = 175,616 w ; w2t = 64*832 us = 26,624 w
    // wt1 = 512*3136 us = 802,816 w
    float* ws = (float*)d_ws;
    int*  gcur = (int*)ws;                          //      2,625 (pad -> 2,688; memset)
    int2* pk0  = (int2*)(ws + 2688);                //  1,612,800 w
    int2* pk1  = (int2*)(ws + 1615488);             //    548,800 w
    float* p1  = ws + 2164288;                      //    627,200
    float* h2  = ws + 2791488;                      //  1,254,400
    unsigned short* p2b = (unsigned short*)(ws + 4045888);  // 175,616 w
    float* z1p = ws + 4221504;                      //    401,408 (7 partials)
    unsigned short* w2t = (unsigned short*)(ws + 4622912);  //  26,624 w
    unsigned short* wt1 = (unsigned short*)(ws + 4649536);  // 802,816 w
    // high water: 5,452,352 words = 21.8 MB

    hipMemsetAsync(gcur, 0, (size_t)NBT * sizeof(int), stream);

    coarse_bin<<<592, 512, 0, stream>>>(ei0, ei1, ps0, ps1, gcur, pk0, pk1,
                                        fc1w, W2, root2, wt1, w2t);
    conv1_pool<<<NB0, 256, 0, stream>>>(pk0, gcur, x, W1, root1, b1, p1);
    conv2_fused<<<NB1, 512, 0, stream>>>(p1, pk1, gcur + NB0, w2t, b2v, h2);
    pool2b<<<(112 * FC1_IN + 255) / 256, 256, 0, stream>>>(h2, p2b);
    gemm_fc1<<<dim3(8, 7, KZ), 256, 0, stream>>>(p2b, wt1, z1p);
    fc2_lsm<<<BSZ, 640, 0, stream>>>(z1p, fc1b, fc2w, fc2b, (float*)d_out);
}

// Round 12
// 184.702 us; speedup vs baseline: 1.1015x; 1.0093x over previous
//
#include <hip/hip_runtime.h>
#include <hip/hip_bf16.h>

#define KK 5
constexpr int N0 = 78400;     // B*28*28
constexpr int E0 = 627200;    // N0*8
constexpr int N1 = 19600;     // B*14*14
constexpr int E1 = 156800;    // N1*8
constexpr int C1 = 32, C2 = 64;
constexpr int BSZ = 100;
constexpr int FC1_IN = 3136, FC1_OUT = 512;
constexpr int KEXT = 832;     // 800 tap-space + 32 root channels
constexpr int ULS = 836;      // LDS int/fp32 U row stride
constexpr int UBS = 856;      // LDS bf16 U row stride (ushorts)
constexpr int KZ = 7;         // fc1 K-splits

// block-granularity buckets (no fine sort; conv blocks consume unordered)
constexpr int NB0 = 1400;     // E0: 56-node buckets (conv1 block = bucket)
constexpr int CAP0 = 576;     // mean 448 + 6 sigma
constexpr int NB1 = 1225;     // E1: 16-node buckets (conv2 block = bucket)
constexpr int CAP1 = 224;     // mean 128 + 8.5 sigma
constexpr int NBT = NB0 + NB1;  // 2625 counters

constexpr float SC1  = 4194304.f;  // 2^22 conv1 fixed-point scale (r8-proven)
constexpr float ISC1 = 1.f / 4194304.f;
constexpr float SC2  = 1048576.f;  // 2^20 conv2 scale (range headroom)
constexpr float ISC2 = 1.f / 1048576.f;

typedef __attribute__((ext_vector_type(8))) short bf16x8;
typedef __attribute__((ext_vector_type(4))) float f32x4;

__device__ __forceinline__ unsigned short f2bf(float f) {
    union { float f; unsigned u; } v; v.f = f;
    unsigned u = v.u;
    unsigned r = (u + 0x7FFF + ((u >> 16) & 1)) >> 16;   // RNE
    return (unsigned short)r;
}

// order-preserving fp32<->uint encoding for atomicMax pooling
__device__ __forceinline__ unsigned fenc(float f) {
    unsigned u = __float_as_uint(f);
    return (u & 0x80000000u) ? ~u : (u | 0x80000000u);
}
__device__ __forceinline__ unsigned short fdec_bf(unsigned e) {
    unsigned u = (e & 0x80000000u) ? (e & 0x7FFFFFFFu) : ~e;
    return f2bf(__uint_as_float(u));
}

__device__ __forceinline__ void taps4(float px, float py,
                                      int& a00, int& a01, int& a10, int& a11,
                                      float& fx, float& fy) {
    float kfx = floorf(px), kfy = floorf(py);
    fx = px - kfx; fy = py - kfy;
    int k0x = min(max((int)kfx, 0), KK - 1);
    int k0y = min(max((int)kfy, 0), KK - 1);
    int k1x = min(k0x + 1, KK - 1), k1y = min(k0y + 1, KK - 1);
    a00 = k0x * KK + k0y; a01 = k0x * KK + k1y;
    a10 = k1x * KK + k0y; a11 = k1x * KK + k1y;
}

// ---- single-pass binning + weight prep + pmax init, one launch:
//  [0,192):   edge scatter into per-conv-block buckets
//  [192,584): wt1 transpose (392)
//  [584,592): w2t build
//  [592,600): pmax init (encoded -inf; pad rows 100-111 = encoded 0)
__global__ void coarse_bin(const int* __restrict__ ei0, const int* __restrict__ ei1,
                           const float* __restrict__ ps0, const float* __restrict__ ps1,
                           int* __restrict__ gcur,
                           int2* __restrict__ pk0, int2* __restrict__ pk1,
                           const float* __restrict__ fc1w, const float* __restrict__ W2,
                           const float* __restrict__ root2,
                           unsigned short* __restrict__ wt1,
                           unsigned short* __restrict__ w2t,
                           unsigned* __restrict__ pmax) {
    __shared__ int hist[NBT];          // 10.5 KB
    __shared__ int gbase[NBT];         // 10.5 KB
    __shared__ unsigned short tile[64 * 66];
    int t = threadIdx.x;               // 512 threads
    if (blockIdx.x >= 192) {
        int pb = blockIdx.x - 192;
        if (pb >= 400) {               // ---- pmax init: 8 blocks ----
            for (int idx = (pb - 400) * 512 + t; idx < 112 * FC1_IN; idx += 8 * 512)
                pmax[idx] = (idx < 100 * FC1_IN) ? 0x007FFFFFu   // enc(-inf)
                                                 : 0x80000000u;  // enc(0.0f)
            return;
        }
        if (pb >= 392) {               // ---- w2t: 8 blocks x 6656 elems ----
            int base = (pb - 392) * 6656;
            for (int i2 = t; i2 < 6656; i2 += 512) {
                int idx = base + i2;
                int o = idx / KEXT, k = idx - o * KEXT;
                float v = (k < 800) ? W2[k * 64 + o] : root2[(k - 800) * 64 + o];
                w2t[idx] = f2bf(v);
            }
            return;
        }
        // ---- wt1 transpose: 392 blocks = 49 k-tiles x 8 j-tiles ----
        int k0 = (pb >> 3) * 64, j0 = (pb & 7) * 64;
        int jj = t & 63, ks = t >> 6;  // ks 0..7
        for (int kk = ks; kk < 64; kk += 8)
            tile[kk * 66 + jj] = f2bf(fc1w[(k0 + kk) * FC1_OUT + j0 + jj]);
        __syncthreads();
        int kk2 = t & 63, js = t >> 6;
        for (int j2 = js; j2 < 64; j2 += 8)
            wt1[(j0 + j2) * FC1_IN + k0 + kk2] = tile[kk2 * 66 + j2];
        return;
    }
    for (int i = t; i < NBT; i += 512) hist[i] = 0;
    __syncthreads();
    int e0b = blockIdx.x * 4096;
    int keys[8], rnk[8], pay0[8], pay1[8];
#pragma unroll
    for (int j = 0; j < 8; j++) {
        int e = e0b + t + j * 512;
        int k = -1, p0 = 0, p1v = 0;
        if (e < E0) {
            int dst = ei0[E0 + e];
            int b = dst / 56, low = dst - b * 56;       // low: 6 bits
            k = b;
            float px = ps0[2 * e] * 4.f, py = ps0[2 * e + 1] * 4.f;
            unsigned ux = min((unsigned)(px * 16384.f + 0.5f), 65535u);
            unsigned uy = min((unsigned)(py * 16384.f + 0.5f), 65535u);
            p0 = ei0[e] | (low << 20); p1v = (int)(ux | (uy << 16));
        } else if (e < E0 + E1) {
            int el = e - E0;
            int dst = ei1[E1 + el];
            k = NB0 + (dst >> 4);                       // 16-node bucket
            float px = ps1[2 * el] * 4.f, py = ps1[2 * el + 1] * 4.f;
            unsigned ux = min((unsigned)(px * 16384.f + 0.5f), 65535u);
            unsigned uy = min((unsigned)(py * 16384.f + 0.5f), 65535u);
            p0 = ei1[el] | ((dst & 15) << 20); p1v = (int)(ux | (uy << 16));
        }
        keys[j] = k; pay0[j] = p0; pay1[j] = p1v;
    }
#pragma unroll
    for (int j = 0; j < 8; j++)
        if (keys[j] >= 0) rnk[j] = atomicAdd(&hist[keys[j]], 1);   // native ds_add
    __syncthreads();
    for (int i = t; i < NBT; i += 512)
        gbase[i] = hist[i] ? atomicAdd(&gcur[i], hist[i]) : 0;
    __syncthreads();
#pragma unroll
    for (int j = 0; j < 8; j++) {
        if (keys[j] >= 0) {
            int k = keys[j];
            int p = gbase[k] + rnk[j];
            if (k < NB0) {
                if (p < CAP0) pk0[k * CAP0 + p] = make_int2(pay0[j], pay1[j]);
            } else {
                if (p < CAP1) pk1[(k - NB0) * CAP1 + p] = make_int2(pay0[j], pay1[j]);
            }
        }
    }
}

// ---- conv1 + pool1: block = bucket = 56 nodes. Unordered edge consumption
//      via LDS int32 fixed-point atomics (associative -> deterministic). ----
__global__ __launch_bounds__(256, 6)
void conv1_pool(const int2* __restrict__ pk0, const int* __restrict__ cnt0,
                const float* __restrict__ x,
                const float* __restrict__ W1,
                const float* __restrict__ root, const float* __restrict__ bias,
                float* __restrict__ p1) {
    __shared__ int   Ui[56 * 26];     // 5.8 KB fixed-point taps+deg
    __shared__ float h1t[56 * 32];    // 7.2 KB
    int t = threadIdx.x;
    int bb = blockIdx.x;              // 1400 blocks; nodes bb*56 .. +55
    int n0 = bb * 56;
    for (int i = t; i < 56 * 26; i += 256) Ui[i] = 0;
    __syncthreads();
    int cnt = min(cnt0[bb], CAP0);
    const int2* bkt = pk0 + bb * CAP0;
    for (int j = t; j < cnt; j += 256) {
        int2 r = bkt[j];                              // sequential, coalesced
        int src = r.x & 0xFFFFF, low = (r.x >> 20) & 63;
        float px = (float)((unsigned)r.y & 0xFFFF) * (1.f / 16384.f);
        float py = (float)((unsigned)r.y >> 16) * (1.f / 16384.f);
        int a00, a01, a10, a11; float fx, fy;
        taps4(px, py, a00, a01, a10, a11, fx, fy);
        float xv = x[src];                            // 313KB array: L2-resident
        float gx = 1.f - fx, gy = 1.f - fy;
        int* row = Ui + low * 26;
        atomicAdd(row + a00, __float2int_rn(gx * gy * xv * SC1));
        atomicAdd(row + a01, __float2int_rn(gx * fy * xv * SC1));
        atomicAdd(row + a10, __float2int_rn(fx * gy * xv * SC1));
        atomicAdd(row + a11, __float2int_rn(fx * fy * xv * SC1));
        atomicAdd(row + 25, 1);
    }
    __syncthreads();
    {
        int o = t & 31, ng = t >> 5;
        float w1c[25];
#pragma unroll
        for (int a = 0; a < 25; a++) w1c[a] = W1[a * C1 + o];
        float ro = root[o], bo = bias[o];
        for (int j2 = 0; j2 < 7; j2++) {
            int nl = ng * 7 + j2;
            int n = n0 + nl;
            float acc = 0.f;
#pragma unroll
            for (int a = 0; a < 25; a++) acc += (float)Ui[nl * 26 + a] * w1c[a];
            float invd = ISC1 / fmaxf((float)Ui[nl * 26 + 25], 1.f);
            float v = acc * invd + x[n] * ro + bo;
            h1t[nl * 32 + o] = v > 0.f ? v : expm1f(v);
        }
    }
    __syncthreads();
    for (int i2 = t; i2 < 448; i2 += 256) {
        int o2 = i2 & 31, pc = i2 >> 5;
        float m0 = h1t[(2 * pc) * 32 + o2],      m1 = h1t[(2 * pc + 1) * 32 + o2];
        float m2 = h1t[(28 + 2 * pc) * 32 + o2], m3 = h1t[(28 + 2 * pc + 1) * 32 + o2];
        p1[(bb * 14 + pc) * C1 + o2] = fmaxf(fmaxf(m0, m1), fmaxf(m2, m3));
    }
}

// ---- conv2 fused (MFMA): block = bucket = 16 nodes, 512 threads.
//      Epilogue pools DIRECTLY via order-encoded global atomicMax into pmax
//      (exact max, associative -> deterministic); h2 buffer + pool2b deleted.
//      Reference pools the 19600 nodes as 25 images of 28x28 -> 14x14. ----
__global__ __launch_bounds__(512, 2)
void conv2_fused(const float* __restrict__ p1, const int2* __restrict__ pk1,
                 const int* __restrict__ cnt1,
                 const unsigned short* __restrict__ w2t,
                 const float* __restrict__ b2, unsigned* __restrict__ pmax) {
    __shared__ int   Ui[16 * ULS];          // 53.5 KB fixed-point (bf16 aliases)
    __shared__ int   es[CAP1];
    __shared__ int   et[CAP1];
    __shared__ float efx[CAP1], efy[CAP1];
    __shared__ int   degc[16];
    unsigned short* Ub = (unsigned short*)Ui;
    int t = threadIdx.x;
    int bx = blockIdx.x;                    // 1225 blocks; nodes bx*16..+15
    int nb = bx * 16;
    int i = t & 31;                         // channel
    int g = t >> 5;                         // node slot 0..15
    int* up = Ui + g * ULS;
#pragma unroll
    for (int a = 0; a < 25; a++) up[a * 32 + i] = 0;
    up[800 + i] = __float2int_rn(p1[(nb + g) * C1 + i] * SC2);   // root channels
    if (t < 16) degc[t] = 0;
    __syncthreads();
    int cnt = min(cnt1[bx], CAP1);
    for (int j = t; j < cnt; j += 512) {
        int2 r = pk1[bx * CAP1 + j];                  // sequential, coalesced
        es[j] = r.x;                                  // src | node<<20
        float px = (float)((unsigned)r.y & 0xFFFF) * (1.f / 16384.f);
        float py = (float)((unsigned)r.y >> 16) * (1.f / 16384.f);
        int a00, a01, a10, a11; float fx, fy;
        taps4(px, py, a00, a01, a10, a11, fx, fy);
        et[j] = a00 | (a01 << 5) | (a10 << 10) | (a11 << 15);
        efx[j] = fx; efy[j] = fy;
        atomicAdd(&degc[(r.x >> 20) & 15], 1);
    }
    __syncthreads();
    // accumulate: thread (slot g, ch i) walks edges g, g+16, ...
    for (int j = g; j < cnt; j += 16) {
        int rx = es[j];
        float xv = p1[(rx & 0xFFFFF) * C1 + i];
        int* row = Ui + ((rx >> 20) & 15) * ULS;
        int m = et[j];
        float fx = efx[j], fy = efy[j];
        float gx = 1.f - fx, gy = 1.f - fy;
        atomicAdd(row + (m & 31) * 32 + i,         __float2int_rn(gx * gy * xv * SC2));
        atomicAdd(row + ((m >> 5) & 31) * 32 + i,  __float2int_rn(gx * fy * xv * SC2));
        atomicAdd(row + ((m >> 10) & 31) * 32 + i, __float2int_rn(fx * gy * xv * SC2));
        atomicAdd(row + ((m >> 15) & 31) * 32 + i, __float2int_rn(fx * fy * xv * SC2));
    }
    __syncthreads();
    // phase 1.5: int fixed-point -> bf16 (invd folded into tap part)
    {
        int g2 = t >> 5, i2c = t & 31;
        float invd = 1.f / fmaxf((float)degc[g2], 1.f);
        float stap = ISC2 * invd;
        const int* srcp = Ui + g2 * ULS + i2c * 26;
        float rv[26];
#pragma unroll
        for (int j = 0; j < 26; j++) {
            float v = (float)srcp[j];
            rv[j] = (i2c * 26 + j < 800) ? v * stap : v * ISC2;
        }
        __syncthreads();
        unsigned* dstp = (unsigned*)(Ub + g2 * UBS + i2c * 26);
#pragma unroll
        for (int j = 0; j < 13; j++) {
            unsigned lo = f2bf(rv[2 * j]), hi = f2bf(rv[2 * j + 1]);
            dstp[j] = lo | (hi << 16);
        }
    }
    __syncthreads();
    // phase 2: MFMA, waves 0-3. D[node=quad*4+r][o=wv*16+(lane&15)]
    int wv = t >> 6, lane = t & 63, quad = lane >> 4, lrow = lane & 15;
    if (wv < 4) {
        f32x4 acc = {0.f, 0.f, 0.f, 0.f};
        const unsigned short* bbase = w2t + (wv * 16 + lrow) * KEXT;
        const unsigned short* abase = Ub + lrow * UBS;   // A row = node lrow
#pragma unroll
        for (int kc = 0; kc < 26; kc++) {
            bf16x8 a = *(const bf16x8*)(abase + kc * 32 + quad * 8);
            bf16x8 b = *(const bf16x8*)(bbase + kc * 32 + quad * 8);
            acc = __builtin_amdgcn_mfma_f32_16x16x32_bf16(a, b, acc, 0, 0, 0);
        }
        int o = wv * 16 + lrow;
        float bo = b2[o];
#pragma unroll
        for (int r = 0; r < 4; r++) {
            int node = quad * 4 + r;
            float v = acc[r] + bo;
            v = v > 0.f ? v : expm1f(v);
            int n1 = nb + node;
            int b28 = n1 / 784;
            int rem = n1 - b28 * 784;
            int rr = rem / 28, cc = rem - rr * 28;
            int flat = ((b28 * 14 + (rr >> 1)) * 14 + (cc >> 1)) * 64 + o;
            atomicMax(&pmax[flat], fenc(v));
        }
    }
}

// ---- fc1 MFMA: pooled A decoded from pmax during staging; 7 kz splits. ----
__global__ void gemm_fc1(const unsigned* __restrict__ pmax,
                         const unsigned short* __restrict__ wt1,
                         float* __restrict__ z1p) {
    constexpr int AS = 232;
    __shared__ unsigned short as_[16 * AS];
    int t = threadIdx.x;
    int jt = blockIdx.x, mt = blockIdx.y, kz = blockIdx.z;
    int wv = t >> 6, lane = t & 63, quad = lane >> 4, lrow = lane & 15;
    int m0 = mt * 16;
    int kbase = kz * 448;
    const unsigned short* bbase = wt1 + (jt * 64 + wv * 16 + lrow) * FC1_IN + kbase;
    f32x4 acc = {0.f, 0.f, 0.f, 0.f};
    for (int ch = 0; ch < 2; ch++) {
        __syncthreads();
        for (int slot = t; slot < 448; slot += 256) {
            int r = slot / 28, c = slot - (slot / 28) * 28;
            const unsigned* gp = pmax + (m0 + r) * FC1_IN + kbase + ch * 224 + c * 8;
            uint4 e0 = *(const uint4*)gp;
            uint4 e1 = *(const uint4*)(gp + 4);
            unsigned w0 = (unsigned)fdec_bf(e0.x) | ((unsigned)fdec_bf(e0.y) << 16);
            unsigned w1 = (unsigned)fdec_bf(e0.z) | ((unsigned)fdec_bf(e0.w) << 16);
            unsigned w2 = (unsigned)fdec_bf(e1.x) | ((unsigned)fdec_bf(e1.y) << 16);
            unsigned w3 = (unsigned)fdec_bf(e1.z) | ((unsigned)fdec_bf(e1.w) << 16);
            *(uint4*)(as_ + r * AS + c * 8) = make_uint4(w0, w1, w2, w3);
        }
        __syncthreads();
        const unsigned short* ab = as_ + lrow * AS;
        const unsigned short* bb = bbase + ch * 224;
#pragma unroll
        for (int kk = 0; kk < 7; kk++) {
            bf16x8 a = *(const bf16x8*)(ab + kk * 32 + quad * 8);
            bf16x8 b = *(const bf16x8*)(bb + kk * 32 + quad * 8);
            acc = __builtin_amdgcn_mfma_f32_16x16x32_bf16(a, b, acc, 0, 0, 0);
        }
    }
    int n = jt * 64 + wv * 16 + lrow;
#pragma unroll
    for (int r = 0; r < 4; r++) {
        int m = m0 + quad * 4 + r;
        z1p[kz * (112 * FC1_OUT) + m * FC1_OUT + n] = acc[r];
    }
}

// ---- fc2 + log_softmax fused; sums 7 fc1 partials, applies fc1 bias+ELU ----
__global__ void fc2_lsm(const float* __restrict__ z1p, const float* __restrict__ fc1b,
                        const float* __restrict__ w, const float* __restrict__ fc2b,
                        float* __restrict__ out) {
    int b = blockIdx.x;
    int t = threadIdx.x;
    int wv = t >> 6;
    int lane = t & 63;
    float acc = 0.f;
#pragma unroll
    for (int m = 0; m < 8; m++) {
        int k = lane * 8 + m;
        float xv = fc1b[k];
#pragma unroll
        for (int p = 0; p < KZ; p++)
            xv += z1p[p * (112 * FC1_OUT) + b * FC1_OUT + k];
        xv = xv > 0.f ? xv : expm1f(xv);
        acc += xv * w[k * 10 + wv];
    }
#pragma unroll
    for (int off = 32; off > 0; off >>= 1) acc += __shfl_down(acc, off);
    __shared__ float zs[10];
    if (lane == 0) {
        float z = acc + fc2b[wv];
        zs[wv] = z > 0.f ? z : expm1f(z);
    }
    __syncthreads();
    if (t < 10) {
        float m = -1e30f;
        for (int jj = 0; jj < 10; jj++) m = fmaxf(m, zs[jj]);
        float s = 0.f;
        for (int jj = 0; jj < 10; jj++) s += expf(zs[jj] - m);
        out[b * 10 + t] = zs[t] - m - logf(s);
    }
}

extern "C" void kernel_launch(void* const* d_in, const int* in_sizes, int n_in,
                              void* d_out, int out_size, void* d_ws, size_t ws_size,
                              hipStream_t stream) {
    const float* x     = (const float*)d_in[0];
    const float* ps0   = (const float*)d_in[1];
    const float* ps1   = (const float*)d_in[2];
    const float* W1    = (const float*)d_in[3];
    const float* root1 = (const float*)d_in[4];
    const float* b1    = (const float*)d_in[5];
    const float* W2    = (const float*)d_in[6];
    const float* root2 = (const float*)d_in[7];
    const float* b2v   = (const float*)d_in[8];
    const float* fc1w  = (const float*)d_in[9];
    const float* fc1b  = (const float*)d_in[10];
    const float* fc2w  = (const float*)d_in[11];
    const float* fc2b  = (const float*)d_in[12];
    const int*   ei0   = (const int*)d_in[13];
    const int*   ei1   = (const int*)d_in[14];

    // Workspace layout — ALL extents in 4-byte WORDS (ushort arrays: count/2).
    // pk0 = 1400*576 int2 = 1,612,800 w ; pk1 = 1225*224 int2 = 548,800 w
    // pmax = 112*3136 uint = 351,232 w ; w2t = 64*832 us = 26,624 w
    // wt1 = 512*3136 us = 802,816 w
    float* ws = (float*)d_ws;
    int*  gcur = (int*)ws;                          //      2,625 (pad -> 2,688; memset)
    int2* pk0  = (int2*)(ws + 2688);                //  1,612,800 w
    int2* pk1  = (int2*)(ws + 1615488);             //    548,800 w
    float* p1  = ws + 2164288;                      //    627,200
    unsigned* pmax = (unsigned*)(ws + 2791488);     //    351,232 w
    float* z1p = ws + 3142720;                      //    401,408 (7 partials)
    unsigned short* w2t = (unsigned short*)(ws + 3544128);  //  26,624 w
    unsigned short* wt1 = (unsigned short*)(ws + 3570752);  // 802,816 w
    // high water: 4,373,568 words = 17.5 MB

    hipMemsetAsync(gcur, 0, (size_t)NBT * sizeof(int), stream);

    coarse_bin<<<600, 512, 0, stream>>>(ei0, ei1, ps0, ps1, gcur, pk0, pk1,
                                        fc1w, W2, root2, wt1, w2t, pmax);
    conv1_pool<<<NB0, 256, 0, stream>>>(pk0, gcur, x, W1, root1, b1, p1);
    conv2_fused<<<NB1, 512, 0, stream>>>(p1, pk1, gcur + NB0, w2t, b2v, pmax);
    gemm_fc1<<<dim3(8, 7, KZ), 256, 0, stream>>>(pmax, wt1, z1p);
    fc2_lsm<<<BSZ, 640, 0, stream>>>(z1p, fc1b, fc2w, fc2b, (float*)d_out);
}

// Round 13
// 184.055 us; speedup vs baseline: 1.1054x; 1.0035x over previous
//
#include <hip/hip_runtime.h>
#include <hip/hip_bf16.h>

#define KK 5
constexpr int N0 = 78400;     // B*28*28
constexpr int E0 = 627200;    // N0*8
constexpr int N1 = 19600;     // B*14*14
constexpr int E1 = 156800;    // N1*8
constexpr int C1 = 32, C2 = 64;
constexpr int BSZ = 100;
constexpr int FC1_IN = 3136, FC1_OUT = 512;
constexpr int KEXT = 832;     // 800 tap-space + 32 root channels
constexpr int ULS = 836;      // LDS int/fp32 U row stride
constexpr int UBS = 856;      // LDS bf16 U row stride (ushorts)
constexpr int KZ = 7;         // fc1 K-splits

// block-granularity buckets (no fine sort; conv blocks consume unordered)
constexpr int NB0 = 1400;     // E0: 56-node buckets (conv1 block = bucket)
constexpr int CAP0 = 576;     // mean 448 + 6 sigma
constexpr int NB1 = 1225;     // E1: 16-node buckets (conv2 block = bucket)
constexpr int CAP1 = 224;     // mean 128 + 8.5 sigma
constexpr int NBT = NB0 + NB1;  // 2625 counters

constexpr float SC1  = 4194304.f;  // 2^22 conv1 fixed-point scale (r8-proven)
constexpr float ISC1 = 1.f / 4194304.f;
constexpr float SC2  = 1048576.f;  // 2^20 conv2 scale (range headroom)
constexpr float ISC2 = 1.f / 1048576.f;

typedef __attribute__((ext_vector_type(8))) short bf16x8;
typedef __attribute__((ext_vector_type(4))) float f32x4;

__device__ __forceinline__ unsigned short f2bf(float f) {
    union { float f; unsigned u; } v; v.f = f;
    unsigned u = v.u;
    unsigned r = (u + 0x7FFF + ((u >> 16) & 1)) >> 16;   // RNE
    return (unsigned short)r;
}
__device__ __forceinline__ float bf2f(unsigned short h) {
    return __uint_as_float(((unsigned)h) << 16);
}

// order-preserving fp32<->uint encoding for atomicMax pooling
__device__ __forceinline__ unsigned fenc(float f) {
    unsigned u = __float_as_uint(f);
    return (u & 0x80000000u) ? ~u : (u | 0x80000000u);
}
__device__ __forceinline__ unsigned short fdec_bf(unsigned e) {
    unsigned u = (e & 0x80000000u) ? (e & 0x7FFFFFFFu) : ~e;
    return f2bf(__uint_as_float(u));
}

__device__ __forceinline__ void taps4(float px, float py,
                                      int& a00, int& a01, int& a10, int& a11,
                                      float& fx, float& fy) {
    float kfx = floorf(px), kfy = floorf(py);
    fx = px - kfx; fy = py - kfy;
    int k0x = min(max((int)kfx, 0), KK - 1);
    int k0y = min(max((int)kfy, 0), KK - 1);
    int k1x = min(k0x + 1, KK - 1), k1y = min(k0y + 1, KK - 1);
    a00 = k0x * KK + k0y; a01 = k0x * KK + k1y;
    a10 = k1x * KK + k0y; a11 = k1x * KK + k1y;
}

// ---- single-pass binning + weight prep + pmax init, one launch:
//  [0,192):   edge scatter into per-conv-block buckets
//  [192,584): wt1 transpose (392)
//  [584,592): w2t build
//  [592,600): pmax init (encoded -inf; pad rows 100-111 = encoded 0)
__global__ void coarse_bin(const int* __restrict__ ei0, const int* __restrict__ ei1,
                           const float* __restrict__ ps0, const float* __restrict__ ps1,
                           int* __restrict__ gcur,
                           int2* __restrict__ pk0, int2* __restrict__ pk1,
                           const float* __restrict__ fc1w, const float* __restrict__ W2,
                           const float* __restrict__ root2,
                           unsigned short* __restrict__ wt1,
                           unsigned short* __restrict__ w2t,
                           unsigned* __restrict__ pmax) {
    __shared__ int hist[NBT];          // 10.5 KB
    __shared__ int gbase[NBT];         // 10.5 KB
    __shared__ unsigned short tile[64 * 66];
    int t = threadIdx.x;               // 512 threads
    if (blockIdx.x >= 192) {
        int pb = blockIdx.x - 192;
        if (pb >= 400) {               // ---- pmax init: 8 blocks ----
            for (int idx = (pb - 400) * 512 + t; idx < 112 * FC1_IN; idx += 8 * 512)
                pmax[idx] = (idx < 100 * FC1_IN) ? 0x007FFFFFu   // enc(-inf)
                                                 : 0x80000000u;  // enc(0.0f)
            return;
        }
        if (pb >= 392) {               // ---- w2t: 8 blocks x 6656 elems ----
            int base = (pb - 392) * 6656;
            for (int i2 = t; i2 < 6656; i2 += 512) {
                int idx = base + i2;
                int o = idx / KEXT, k = idx - o * KEXT;
                float v = (k < 800) ? W2[k * 64 + o] : root2[(k - 800) * 64 + o];
                w2t[idx] = f2bf(v);
            }
            return;
        }
        // ---- wt1 transpose: 392 blocks = 49 k-tiles x 8 j-tiles ----
        int k0 = (pb >> 3) * 64, j0 = (pb & 7) * 64;
        int jj = t & 63, ks = t >> 6;  // ks 0..7
        for (int kk = ks; kk < 64; kk += 8)
            tile[kk * 66 + jj] = f2bf(fc1w[(k0 + kk) * FC1_OUT + j0 + jj]);
        __syncthreads();
        int kk2 = t & 63, js = t >> 6;
        for (int j2 = js; j2 < 64; j2 += 8)
            wt1[(j0 + j2) * FC1_IN + k0 + kk2] = tile[kk2 * 66 + j2];
        return;
    }
    for (int i = t; i < NBT; i += 512) hist[i] = 0;
    __syncthreads();
    int e0b = blockIdx.x * 4096;
    int keys[8], rnk[8], pay0[8], pay1[8];
#pragma unroll
    for (int j = 0; j < 8; j++) {
        int e = e0b + t + j * 512;
        int k = -1, p0 = 0, p1v = 0;
        if (e < E0) {
            int dst = ei0[E0 + e];
            int b = dst / 56, low = dst - b * 56;       // low: 6 bits
            k = b;
            float px = ps0[2 * e] * 4.f, py = ps0[2 * e + 1] * 4.f;
            unsigned ux = min((unsigned)(px * 16384.f + 0.5f), 65535u);
            unsigned uy = min((unsigned)(py * 16384.f + 0.5f), 65535u);
            p0 = ei0[e] | (low << 20); p1v = (int)(ux | (uy << 16));
        } else if (e < E0 + E1) {
            int el = e - E0;
            int dst = ei1[E1 + el];
            k = NB0 + (dst >> 4);                       // 16-node bucket
            float px = ps1[2 * el] * 4.f, py = ps1[2 * el + 1] * 4.f;
            unsigned ux = min((unsigned)(px * 16384.f + 0.5f), 65535u);
            unsigned uy = min((unsigned)(py * 16384.f + 0.5f), 65535u);
            p0 = ei1[el] | ((dst & 15) << 20); p1v = (int)(ux | (uy << 16));
        }
        keys[j] = k; pay0[j] = p0; pay1[j] = p1v;
    }
#pragma unroll
    for (int j = 0; j < 8; j++)
        if (keys[j] >= 0) rnk[j] = atomicAdd(&hist[keys[j]], 1);   // native ds_add
    __syncthreads();
    for (int i = t; i < NBT; i += 512)
        gbase[i] = hist[i] ? atomicAdd(&gcur[i], hist[i]) : 0;
    __syncthreads();
#pragma unroll
    for (int j = 0; j < 8; j++) {
        if (keys[j] >= 0) {
            int k = keys[j];
            int p = gbase[k] + rnk[j];
            if (k < NB0) {
                if (p < CAP0) pk0[k * CAP0 + p] = make_int2(pay0[j], pay1[j]);
            } else {
                if (p < CAP1) pk1[(k - NB0) * CAP1 + p] = make_int2(pay0[j], pay1[j]);
            }
        }
    }
}

// ---- conv1 + pool1: block = bucket = 56 nodes. Unordered edge consumption
//      via LDS int32 fixed-point atomics (associative -> deterministic).
//      p1 stored BF16 (64B rows): conv2's random gather traffic halves. ----
__global__ __launch_bounds__(256, 6)
void conv1_pool(const int2* __restrict__ pk0, const int* __restrict__ cnt0,
                const float* __restrict__ x,
                const float* __restrict__ W1,
                const float* __restrict__ root, const float* __restrict__ bias,
                unsigned short* __restrict__ p1b) {
    __shared__ int   Ui[56 * 26];     // 5.8 KB fixed-point taps+deg
    __shared__ float h1t[56 * 32];    // 7.2 KB
    int t = threadIdx.x;
    int bb = blockIdx.x;              // 1400 blocks; nodes bb*56 .. +55
    int n0 = bb * 56;
    for (int i = t; i < 56 * 26; i += 256) Ui[i] = 0;
    __syncthreads();
    int cnt = min(cnt0[bb], CAP0);
    const int2* bkt = pk0 + bb * CAP0;
    for (int j = t; j < cnt; j += 256) {
        int2 r = bkt[j];                              // sequential, coalesced
        int src = r.x & 0xFFFFF, low = (r.x >> 20) & 63;
        float px = (float)((unsigned)r.y & 0xFFFF) * (1.f / 16384.f);
        float py = (float)((unsigned)r.y >> 16) * (1.f / 16384.f);
        int a00, a01, a10, a11; float fx, fy;
        taps4(px, py, a00, a01, a10, a11, fx, fy);
        float xv = x[src];                            // 313KB array: L2-resident
        float gx = 1.f - fx, gy = 1.f - fy;
        int* row = Ui + low * 26;
        atomicAdd(row + a00, __float2int_rn(gx * gy * xv * SC1));
        atomicAdd(row + a01, __float2int_rn(gx * fy * xv * SC1));
        atomicAdd(row + a10, __float2int_rn(fx * gy * xv * SC1));
        atomicAdd(row + a11, __float2int_rn(fx * fy * xv * SC1));
        atomicAdd(row + 25, 1);
    }
    __syncthreads();
    {
        int o = t & 31, ng = t >> 5;
        float w1c[25];
#pragma unroll
        for (int a = 0; a < 25; a++) w1c[a] = W1[a * C1 + o];
        float ro = root[o], bo = bias[o];
        for (int j2 = 0; j2 < 7; j2++) {
            int nl = ng * 7 + j2;
            int n = n0 + nl;
            float acc = 0.f;
#pragma unroll
            for (int a = 0; a < 25; a++) acc += (float)Ui[nl * 26 + a] * w1c[a];
            float invd = ISC1 / fmaxf((float)Ui[nl * 26 + 25], 1.f);
            float v = acc * invd + x[n] * ro + bo;
            h1t[nl * 32 + o] = v > 0.f ? v : expm1f(v);
        }
    }
    __syncthreads();
    for (int i2 = t; i2 < 448; i2 += 256) {
        int o2 = i2 & 31, pc = i2 >> 5;
        float m0 = h1t[(2 * pc) * 32 + o2],      m1 = h1t[(2 * pc + 1) * 32 + o2];
        float m2 = h1t[(28 + 2 * pc) * 32 + o2], m3 = h1t[(28 + 2 * pc + 1) * 32 + o2];
        p1b[(bb * 14 + pc) * C1 + o2] = f2bf(fmaxf(fmaxf(m0, m1), fmaxf(m2, m3)));
    }
}

// ---- conv2 fused (MFMA): block = bucket = 16 nodes, 512 threads.
//      Gather reads BF16 p1 rows (64B). Epilogue pools via order-encoded
//      global atomicMax into pmax (exact max, deterministic). ----
__global__ __launch_bounds__(512, 2)
void conv2_fused(const unsigned short* __restrict__ p1b, const int2* __restrict__ pk1,
                 const int* __restrict__ cnt1,
                 const unsigned short* __restrict__ w2t,
                 const float* __restrict__ b2, unsigned* __restrict__ pmax) {
    __shared__ int   Ui[16 * ULS];          // 53.5 KB fixed-point (bf16 aliases)
    __shared__ int   es[CAP1];
    __shared__ int   et[CAP1];
    __shared__ float efx[CAP1], efy[CAP1];
    __shared__ int   degc[16];
    unsigned short* Ub = (unsigned short*)Ui;
    int t = threadIdx.x;
    int bx = blockIdx.x;                    // 1225 blocks; nodes bx*16..+15
    int nb = bx * 16;
    int i = t & 31;                         // channel
    int g = t >> 5;                         // node slot 0..15
    int* up = Ui + g * ULS;
#pragma unroll
    for (int a = 0; a < 25; a++) up[a * 32 + i] = 0;
    up[800 + i] = __float2int_rn(bf2f(p1b[(nb + g) * C1 + i]) * SC2);   // root
    if (t < 16) degc[t] = 0;
    __syncthreads();
    int cnt = min(cnt1[bx], CAP1);
    for (int j = t; j < cnt; j += 512) {
        int2 r = pk1[bx * CAP1 + j];                  // sequential, coalesced
        es[j] = r.x;                                  // src | node<<20
        float px = (float)((unsigned)r.y & 0xFFFF) * (1.f / 16384.f);
        float py = (float)((unsigned)r.y >> 16) * (1.f / 16384.f);
        int a00, a01, a10, a11; float fx, fy;
        taps4(px, py, a00, a01, a10, a11, fx, fy);
        et[j] = a00 | (a01 << 5) | (a10 << 10) | (a11 << 15);
        efx[j] = fx; efy[j] = fy;
        atomicAdd(&degc[(r.x >> 20) & 15], 1);
    }
    __syncthreads();
    // accumulate: thread (slot g, ch i) walks edges g, g+16, ...
    for (int j = g; j < cnt; j += 16) {
        int rx = es[j];
        float xv = bf2f(p1b[(rx & 0xFFFFF) * C1 + i]);
        int* row = Ui + ((rx >> 20) & 15) * ULS;
        int m = et[j];
        float fx = efx[j], fy = efy[j];
        float gx = 1.f - fx, gy = 1.f - fy;
        atomicAdd(row + (m & 31) * 32 + i,         __float2int_rn(gx * gy * xv * SC2));
        atomicAdd(row + ((m >> 5) & 31) * 32 + i,  __float2int_rn(gx * fy * xv * SC2));
        atomicAdd(row + ((m >> 10) & 31) * 32 + i, __float2int_rn(fx * gy * xv * SC2));
        atomicAdd(row + ((m >> 15) & 31) * 32 + i, __float2int_rn(fx * fy * xv * SC2));
    }
    __syncthreads();
    // phase 1.5: int fixed-point -> bf16 (invd folded into tap part)
    {
        int g2 = t >> 5, i2c = t & 31;
        float invd = 1.f / fmaxf((float)degc[g2], 1.f);
        float stap = ISC2 * invd;
        const int* srcp = Ui + g2 * ULS + i2c * 26;
        float rv[26];
#pragma unroll
        for (int j = 0; j < 26; j++) {
            float v = (float)srcp[j];
            rv[j] = (i2c * 26 + j < 800) ? v * stap : v * ISC2;
        }
        __syncthreads();
        unsigned* dstp = (unsigned*)(Ub + g2 * UBS + i2c * 26);
#pragma unroll
        for (int j = 0; j < 13; j++) {
            unsigned lo = f2bf(rv[2 * j]), hi = f2bf(rv[2 * j + 1]);
            dstp[j] = lo | (hi << 16);
        }
    }
    __syncthreads();
    // phase 2: MFMA, waves 0-3. D[node=quad*4+r][o=wv*16+(lane&15)]
    int wv = t >> 6, lane = t & 63, quad = lane >> 4, lrow = lane & 15;
    if (wv < 4) {
        f32x4 acc = {0.f, 0.f, 0.f, 0.f};
        const unsigned short* bbase = w2t + (wv * 16 + lrow) * KEXT;
        const unsigned short* abase = Ub + lrow * UBS;   // A row = node lrow
#pragma unroll
        for (int kc = 0; kc < 26; kc++) {
            bf16x8 a = *(const bf16x8*)(abase + kc * 32 + quad * 8);
            bf16x8 b = *(const bf16x8*)(bbase + kc * 32 + quad * 8);
            acc = __builtin_amdgcn_mfma_f32_16x16x32_bf16(a, b, acc, 0, 0, 0);
        }
        int o = wv * 16 + lrow;
        float bo = b2[o];
#pragma unroll
        for (int r = 0; r < 4; r++) {
            int node = quad * 4 + r;
            float v = acc[r] + bo;
            v = v > 0.f ? v : expm1f(v);
            int n1 = nb + node;
            int b28 = n1 / 784;
            int rem = n1 - b28 * 784;
            int rr = rem / 28, cc = rem - rr * 28;
            int flat = ((b28 * 14 + (rr >> 1)) * 14 + (cc >> 1)) * 64 + o;
            atomicMax(&pmax[flat], fenc(v));
        }
    }
}

// ---- fc1 MFMA: pooled A decoded from pmax during staging; 7 kz splits. ----
__global__ void gemm_fc1(const unsigned* __restrict__ pmax,
                         const unsigned short* __restrict__ wt1,
                         float* __restrict__ z1p) {
    constexpr int AS = 232;
    __shared__ unsigned short as_[16 * AS];
    int t = threadIdx.x;
    int jt = blockIdx.x, mt = blockIdx.y, kz = blockIdx.z;
    int wv = t >> 6, lane = t & 63, quad = lane >> 4, lrow = lane & 15;
    int m0 = mt * 16;
    int kbase = kz * 448;
    const unsigned short* bbase = wt1 + (jt * 64 + wv * 16 + lrow) * FC1_IN + kbase;
    f32x4 acc = {0.f, 0.f, 0.f, 0.f};
    for (int ch = 0; ch < 2; ch++) {
        __syncthreads();
        for (int slot = t; slot < 448; slot += 256) {
            int r = slot / 28, c = slot - (slot / 28) * 28;
            const unsigned* gp = pmax + (m0 + r) * FC1_IN + kbase + ch * 224 + c * 8;
            uint4 e0 = *(const uint4*)gp;
            uint4 e1 = *(const uint4*)(gp + 4);
            unsigned w0 = (unsigned)fdec_bf(e0.x) | ((unsigned)fdec_bf(e0.y) << 16);
            unsigned w1 = (unsigned)fdec_bf(e0.z) | ((unsigned)fdec_bf(e0.w) << 16);
            unsigned w2 = (unsigned)fdec_bf(e1.x) | ((unsigned)fdec_bf(e1.y) << 16);
            unsigned w3 = (unsigned)fdec_bf(e1.z) | ((unsigned)fdec_bf(e1.w) << 16);
            *(uint4*)(as_ + r * AS + c * 8) = make_uint4(w0, w1, w2, w3);
        }
        __syncthreads();
        const unsigned short* ab = as_ + lrow * AS;
        const unsigned short* bb = bbase + ch * 224;
#pragma unroll
        for (int kk = 0; kk < 7; kk++) {
            bf16x8 a = *(const bf16x8*)(ab + kk * 32 + quad * 8);
            bf16x8 b = *(const bf16x8*)(bb + kk * 32 + quad * 8);
            acc = __builtin_amdgcn_mfma_f32_16x16x32_bf16(a, b, acc, 0, 0, 0);
        }
    }
    int n = jt * 64 + wv * 16 + lrow;
#pragma unroll
    for (int r = 0; r < 4; r++) {
        int m = m0 + quad * 4 + r;
        z1p[kz * (112 * FC1_OUT) + m * FC1_OUT + n] = acc[r];
    }
}

// ---- fc2 + log_softmax fused; sums 7 fc1 partials, applies fc1 bias+ELU ----
__global__ void fc2_lsm(const float* __restrict__ z1p, const float* __restrict__ fc1b,
                        const float* __restrict__ w, const float* __restrict__ fc2b,
                        float* __restrict__ out) {
    int b = blockIdx.x;
    int t = threadIdx.x;
    int wv = t >> 6;
    int lane = t & 63;
    float acc = 0.f;
#pragma unroll
    for (int m = 0; m < 8; m++) {
        int k = lane * 8 + m;
        float xv = fc1b[k];
#pragma unroll
        for (int p = 0; p < KZ; p++)
            xv += z1p[p * (112 * FC1_OUT) + b * FC1_OUT + k];
        xv = xv > 0.f ? xv : expm1f(xv);
        acc += xv * w[k * 10 + wv];
    }
#pragma unroll
    for (int off = 32; off > 0; off >>= 1) acc += __shfl_down(acc, off);
    __shared__ float zs[10];
    if (lane == 0) {
        float z = acc + fc2b[wv];
        zs[wv] = z > 0.f ? z : expm1f(z);
    }
    __syncthreads();
    if (t < 10) {
        float m = -1e30f;
        for (int jj = 0; jj < 10; jj++) m = fmaxf(m, zs[jj]);
        float s = 0.f;
        for (int jj = 0; jj < 10; jj++) s += expf(zs[jj] - m);
        out[b * 10 + t] = zs[t] - m - logf(s);
    }
}

extern "C" void kernel_launch(void* const* d_in, const int* in_sizes, int n_in,
                              void* d_out, int out_size, void* d_ws, size_t ws_size,
                              hipStream_t stream) {
    const float* x     = (const float*)d_in[0];
    const float* ps0   = (const float*)d_in[1];
    const float* ps1   = (const float*)d_in[2];
    const float* W1    = (const float*)d_in[3];
    const float* root1 = (const float*)d_in[4];
    const float* b1    = (const float*)d_in[5];
    const float* W2    = (const float*)d_in[6];
    const float* root2 = (const float*)d_in[7];
    const float* b2v   = (const float*)d_in[8];
    const float* fc1w  = (const float*)d_in[9];
    const float* fc1b  = (const float*)d_in[10];
    const float* fc2w  = (const float*)d_in[11];
    const float* fc2b  = (const float*)d_in[12];
    const int*   ei0   = (const int*)d_in[13];
    const int*   ei1   = (const int*)d_in[14];

    // Workspace layout — ALL extents in 4-byte WORDS (ushort arrays: count/2).
    // pk0 = 1400*576 int2 = 1,612,800 w ; pk1 = 1225*224 int2 = 548,800 w
    // p1b = 19600*32 ushorts = 627,200 us = 313,600 w
    // pmax = 112*3136 uint = 351,232 w ; w2t = 64*832 us = 26,624 w
    // wt1 = 512*3136 us = 802,816 w
    float* ws = (float*)d_ws;
    int*  gcur = (int*)ws;                          //      2,625 (pad -> 2,688; memset)
    int2* pk0  = (int2*)(ws + 2688);                //  1,612,800 w
    int2* pk1  = (int2*)(ws + 1615488);             //    548,800 w
    unsigned short* p1b = (unsigned short*)(ws + 2164288);  // 313,600 w
    unsigned* pmax = (unsigned*)(ws + 2477888);     //    351,232 w
    float* z1p = ws + 2829120;                      //    401,408 (7 partials)
    unsigned short* w2t = (unsigned short*)(ws + 3230528);  //  26,624 w
    unsigned short* wt1 = (unsigned short*)(ws + 3257152);  // 802,816 w
    // high water: 4,059,968 words = 16.2 MB

    hipMemsetAsync(gcur, 0, (size_t)NBT * sizeof(int), stream);

    coarse_bin<<<600, 512, 0, stream>>>(ei0, ei1, ps0, ps1, gcur, pk0, pk1,
                                        fc1w, W2, root2, wt1, w2t, pmax);
    conv1_pool<<<NB0, 256, 0, stream>>>(pk0, gcur, x, W1, root1, b1, p1b);
    conv2_fused<<<NB1, 512, 0, stream>>>(p1b, pk1, gcur + NB0, w2t, b2v, pmax);
    gemm_fc1<<<dim3(8, 7, KZ), 256, 0, stream>>>(pmax, wt1, z1p);
    fc2_lsm<<<BSZ, 640, 0, stream>>>(z1p, fc1b, fc2w, fc2b, (float*)d_out);
}